// Round 10
// baseline (180.911 us; speedup 1.0000x reference)
//
#include <hip/hip_runtime.h>
#include <hip/hip_bf16.h>
#include <cstdint>
#include <cstddef>

#define DEVI __device__ __forceinline__

typedef __attribute__((ext_vector_type(8))) short short8;
typedef __attribute__((ext_vector_type(4))) float f32x4;
typedef __attribute__((ext_vector_type(16))) float f32x16;
typedef __attribute__((ext_vector_type(4))) unsigned int u32x4;

constexpr int Bz = 4, Tt = 2048, Fd = 1024, Hh = 16, Dk = 64;
constexpr int Mrows = Bz * Tt;  // 8192
constexpr float QSCALE = 0.18033688011112042f;  // (1/8) * log2(e)

DEVI unsigned short f2bf(float f) {
  union { __hip_bfloat16 h; unsigned short u; } cv;
  cv.h = __float2bfloat16(f);
  return cv.u;
}

DEVI unsigned cvtpk(float a, float b) {  // low = a, high = b, RNE
  unsigned r;
  asm("v_cvt_pk_bf16_f32 %0, %1, %2" : "=v"(r) : "v"(a), "v"(b));
  return r;
}

DEVI void gl_lds16(const void* g, void* s) {
  __builtin_amdgcn_global_load_lds(
      (const __attribute__((address_space(1))) void*)g,
      (__attribute__((address_space(3))) void*)s, 16, 0, 0);
}

// 4 weight matrices fp32->bf16, one launch
__global__ void cvt4_bf16(const float* __restrict__ s0, unsigned short* __restrict__ d0,
                          const float* __restrict__ s1, unsigned short* __restrict__ d1,
                          const float* __restrict__ s2, unsigned short* __restrict__ d2,
                          const float* __restrict__ s3, unsigned short* __restrict__ d3,
                          int n4) {
  const float* src = blockIdx.y == 0 ? s0 : (blockIdx.y == 1 ? s1 : (blockIdx.y == 2 ? s2 : s3));
  unsigned short* dst = blockIdx.y == 0 ? d0 : (blockIdx.y == 1 ? d1 : (blockIdx.y == 2 ? d2 : d3));
  int i = blockIdx.x * blockDim.x + threadIdx.x;
  int stride = gridDim.x * blockDim.x;
  for (; i < n4; i += stride) {
    float4 v = reinterpret_cast<const float4*>(src)[i];
    ushort4 o;
    o.x = f2bf(v.x); o.y = f2bf(v.y); o.z = f2bf(v.z); o.w = f2bf(v.w);
    reinterpret_cast<ushort4*>(dst)[i] = o;
  }
}

// -------- QKV GEMM, fused fp32->bf16 A conversion, 128x256 tile @ 512 threads --------
// [R9 proven best: -3.3us wall] 8 waves (2Mx4N), acc[4][4] (60 VGPR), 48KB LDS,
// 3 blocks/CU; conversion redundancy 4 (vs 8 at BN=128).
// grid.z: 0=Q (scaled), 1=K, 2=V (transposed out).
__global__ __launch_bounds__(512, 2) void gemm_qkvf(
    const float* __restrict__ q32, const float* __restrict__ k32,
    const float* __restrict__ v32, const unsigned short* __restrict__ wq,
    const unsigned short* __restrict__ wk, const unsigned short* __restrict__ wv,
    const float* __restrict__ bq, const float* __restrict__ bk, const float* __restrict__ bv,
    unsigned short* __restrict__ Qb, unsigned short* __restrict__ Kb,
    unsigned short* __restrict__ Vt) {
  constexpr int K = 1024, N = 1024;
  __shared__ __align__(16) unsigned short As[128 * 64];   // 16KB
  __shared__ __align__(16) unsigned short Bs[256 * 64];   // 32KB
  int z = blockIdx.z;
  const float* A32 = z == 0 ? q32 : (z == 1 ? k32 : v32);
  const unsigned short* W = z == 0 ? wq : (z == 1 ? wk : wv);
  const float* bias = z == 0 ? bq : (z == 1 ? bk : bv);
  void* out = z == 0 ? (void*)Qb : (z == 1 ? (void*)Kb : (void*)Vt);
  float scale = z == 0 ? QSCALE : 1.0f;
  int mode = z == 2 ? 2 : 0;

  int f = blockIdx.y * gridDim.x + blockIdx.x;  // 0..255 (64 m-blocks x 4 n-blocks)
  f = (f & 7) * 32 + (f >> 3);                  // XCD-contiguous chunks (256 = 8x32, bijective)
  const int m0 = (f >> 2) * 128, n0 = (f & 3) * 256;
  const int t = threadIdx.x, w = t >> 6, l = t & 63;
  const int wr = w >> 2, wc = w & 3;            // 2 M-waves x 4 N-waves, 64x64 each
  const int lr = l & 15, lg = l >> 4;
  f32x4 acc[4][4] = {};

  for (int k0 = 0; k0 < K; k0 += 64) {
    __syncthreads();
    // A fp32 loads first (latency overlaps B issue): 128 rows, 512 threads
    float4 fA[2][2];
#pragma unroll
    for (int i = 0; i < 2; ++i) {
      int row = i * 64 + w * 8 + (l >> 3);
      const float* src = A32 + (size_t)(m0 + row) * K + k0 + (l & 7) * 8;
      fA[i][0] = ((const float4*)src)[0];
      fA[i][1] = ((const float4*)src)[1];
    }
    // B via global_load_lds (pre-swizzled source, linear dest): 256 rows x 64 cols
#pragma unroll
    for (int i = 0; i < 4; ++i) {
      int base = i * 8192 + w * 1024;
      int d = base + l * 16;
      int row = d >> 7;
      int srcb = ((l & 7) ^ (row & 7)) << 4;
      gl_lds16((const char*)W + ((size_t)(n0 + row) * K + k0) * 2 + srcb, (char*)Bs + base);
    }
    // A: cvt_pk + swizzled ds_write_b128
#pragma unroll
    for (int i = 0; i < 2; ++i) {
      int row = i * 64 + w * 8 + (l >> 3);
      u32x4 wv4;
      wv4[0] = cvtpk(fA[i][0].x, fA[i][0].y);
      wv4[1] = cvtpk(fA[i][0].z, fA[i][0].w);
      wv4[2] = cvtpk(fA[i][1].x, fA[i][1].y);
      wv4[3] = cvtpk(fA[i][1].z, fA[i][1].w);
      int slot = (l & 7) ^ (row & 7);
      *(u32x4*)((char*)As + row * 128 + slot * 16) = wv4;
    }
    __syncthreads();
#pragma unroll
    for (int kk = 0; kk < 2; ++kk) {
      short8 af[4], bf[4];
#pragma unroll
      for (int i = 0; i < 4; ++i) {
        int ra = wr * 64 + i * 16 + lr;
        int rb = wc * 64 + i * 16 + lr;
        af[i] = *(const short8*)((const char*)As + ra * 128 + (((kk * 4 + lg) ^ (ra & 7)) << 4));
        bf[i] = *(const short8*)((const char*)Bs + rb * 128 + (((kk * 4 + lg) ^ (rb & 7)) << 4));
      }
#pragma unroll
      for (int mi = 0; mi < 4; ++mi)
#pragma unroll
        for (int ni = 0; ni < 4; ++ni)
          acc[mi][ni] = __builtin_amdgcn_mfma_f32_16x16x32_bf16(af[mi], bf[ni], acc[mi][ni], 0, 0, 0);
    }
  }
#pragma unroll
  for (int mi = 0; mi < 4; ++mi)
#pragma unroll
    for (int ni = 0; ni < 4; ++ni) {
      int col = n0 + wc * 64 + ni * 16 + lr;
      float bv = bias[col];
      if (mode == 2) {
        // transposed store into Vt[((b*16+h)*64+d)*2048 + t], 4 consecutive t
        int hh = col >> 6, dd = col & 63;
        int row = m0 + wr * 64 + mi * 16 + lg * 4;
        int bb = row >> 11, t0 = row & 2047;
        ushort4 o;
        o.x = f2bf(acc[mi][ni][0] + bv);
        o.y = f2bf(acc[mi][ni][1] + bv);
        o.z = f2bf(acc[mi][ni][2] + bv);
        o.w = f2bf(acc[mi][ni][3] + bv);
        *(ushort4*)((unsigned short*)out + (((size_t)(bb * Hh + hh) * Dk + dd) << 11) + t0) = o;
      } else {
#pragma unroll
        for (int r = 0; r < 4; ++r) {
          int row = m0 + wr * 64 + mi * 16 + lg * 4 + r;
          ((unsigned short*)out)[(size_t)row * N + col] = f2bf((acc[mi][ni][r] + bv) * scale);
        }
      }
    }
}

// output projection + residual: out = A @ Wo^T + bo + resid (f32)  [proven]
__global__ __launch_bounds__(256, 2) void gemm_out(
    const unsigned short* __restrict__ A, const unsigned short* __restrict__ W,
    const float* __restrict__ bias, const float* __restrict__ resid,
    float* __restrict__ out) {
  constexpr int K = 1024, N = 1024;
  __shared__ __align__(16) unsigned short As[128 * 64];
  __shared__ __align__(16) unsigned short Bs[128 * 64];
  int f = blockIdx.y * gridDim.x + blockIdx.x;
  f = (f & 7) * 64 + (f >> 3);
  const int m0 = (f >> 3) * 128, n0 = (f & 7) * 128;
  const int t = threadIdx.x, w = t >> 6, l = t & 63;
  const int wr = w >> 1, wc = w & 1;
  const int lr = l & 15, lg = l >> 4;
  f32x4 acc[4][4] = {};
  for (int k0 = 0; k0 < K; k0 += 64) {
    __syncthreads();
#pragma unroll
    for (int i = 0; i < 4; ++i) {
      int base = i * 4096 + w * 1024;
      int d = base + l * 16;
      int row = d >> 7;
      int srcb = ((l & 7) ^ (row & 7)) << 4;
      gl_lds16((const char*)A + ((size_t)(m0 + row) * K + k0) * 2 + srcb, (char*)As + base);
      gl_lds16((const char*)W + ((size_t)(n0 + row) * K + k0) * 2 + srcb, (char*)Bs + base);
    }
    __syncthreads();
#pragma unroll
    for (int kk = 0; kk < 2; ++kk) {
      short8 af[4], bf[4];
#pragma unroll
      for (int i = 0; i < 4; ++i) {
        int ra = wr * 64 + i * 16 + lr;
        int rb = wc * 64 + i * 16 + lr;
        af[i] = *(const short8*)((const char*)As + ra * 128 + (((kk * 4 + lg) ^ (ra & 7)) << 4));
        bf[i] = *(const short8*)((const char*)Bs + rb * 128 + (((kk * 4 + lg) ^ (rb & 7)) << 4));
      }
#pragma unroll
      for (int mi = 0; mi < 4; ++mi)
#pragma unroll
        for (int ni = 0; ni < 4; ++ni)
          acc[mi][ni] = __builtin_amdgcn_mfma_f32_16x16x32_bf16(af[mi], bf[ni], acc[mi][ni], 0, 0, 0);
    }
  }
#pragma unroll
  for (int mi = 0; mi < 4; ++mi)
#pragma unroll
    for (int ni = 0; ni < 4; ++ni) {
      int col = n0 + wc * 64 + ni * 16 + lr;
      float bv = bias[col];
#pragma unroll
      for (int r = 0; r < 4; ++r) {
        int row = m0 + wr * 64 + mi * 16 + lg * 4 + r;
        size_t idx = (size_t)row * N + col;
        out[idx] = acc[mi][ni][r] + bv + resid[idx];
      }
    }
}

// -------- Flash attention v14: 4 waves/SIMD (8 waves x 32 q-rows, 2 blocks/CU) --------
// Every prior variant ran at 2 waves/SIMD; the measured 27% stall is the
// per-wave serial chain with too little TLP. v14: 256 q-rows/block, 512
// threads, grid 512 = 2 blocks/CU = 4 waves/SIMD. Ring-4 K/V (64KB LDS x2
// blocks = 128KB), deferred PV, XCD-affinity (8 heads x 8 q-blocks per XCD,
// K/V L2 footprint 4MB). Single Q-group per wave keeps VGPR under the 128 cap.
__global__ __launch_bounds__(512, 4) void attn_kernel(
    const unsigned short* __restrict__ Qb, const unsigned short* __restrict__ Kb,
    const unsigned short* __restrict__ Vt, unsigned short* __restrict__ Ctx) {
  __shared__ __align__(16) unsigned short smem[8 * 4096];  // 64KB: K ring-4 [0..4), V ring-4 at +32KB
  int bid = blockIdx.x;
  const int xcd = bid & 7, idx = bid >> 3;   // hw round-robins blocks across 8 XCDs
  const int bh = xcd * 8 + (idx >> 3);       // 8 heads per XCD
  const int q0 = (idx & 7) * 256;            // 8 q-blocks per head, same XCD
  const int h = bh & 15;
  const int b = bh >> 4;
  const int t = threadIdx.x, w = t >> 6, l = t & 63;
  const int q31 = l & 31, hi = l >> 5;
  const int qbase = q0 + w * 32;

  short8 qf[4];
  {
    const unsigned short* qp = Qb + (size_t)(b * Tt + qbase + q31) * Fd + h * Dk;
#pragma unroll
    for (int c = 0; c < 4; ++c) qf[c] = *(const short8*)(qp + c * 16 + hi * 8);
  }

  int koff[8];
#pragma unroll
  for (int g = 0; g < 2; ++g)
#pragma unroll
    for (int c = 0; c < 4; ++c) {
      int row = g * 32 + q31;
      koff[g * 4 + c] = row * 128 + ((c * 32 + hi * 16) ^ ((row & 7) << 4));
    }

  const size_t kbase = (size_t)(b * Tt) * Fd + h * Dk;
  const size_t vbase = (size_t)((b * Hh + h) * Dk) * Tt;

  f32x16 O0{}, O1{};
  short8 pf[4];  // packed P(t-1), held across the barrier
  float lsA = 0.f, lsB = 0.f;

  auto kbuf = [&](int kt) { return (const char*)smem + ((kt & 3) << 13); };
  auto vbuf = [&](int kt) { return (const char*)smem + 32768 + ((kt & 3) << 13); };

  // 8 waves cover 8KB K + 8KB V: 1KB per wave each (2 gl_lds/thread)
  auto stage = [&](int kt) {
    char* Kd = (char*)smem + ((kt & 3) << 13);
    char* Vd = (char*)smem + 32768 + ((kt & 3) << 13);
    int base = w * 1024;
    int d0 = base + l * 16;
    int row = d0 >> 7, inb = d0 & 127;
    int srcb = inb ^ ((row & 7) << 4);
    gl_lds16((const char*)Kb + (kbase + (size_t)(kt * 64 + row) * Fd) * 2 + srcb, Kd + base);
    gl_lds16((const char*)Vt + (vbase + (size_t)row * Tt + kt * 64) * 2 + srcb, Vd + base);
  };

  auto qk = [&](int kt, f32x16& S0, f32x16& S1) {
    const char* Kd = kbuf(kt);
    __builtin_amdgcn_s_setprio(1);
#pragma unroll
    for (int c = 0; c < 4; ++c) {
      short8 k0 = *(const short8*)(Kd + koff[c]);
      short8 k1 = *(const short8*)(Kd + koff[4 + c]);
      S0 = __builtin_amdgcn_mfma_f32_32x32x16_bf16(k0, qf[c], S0, 0, 0, 0);
      S1 = __builtin_amdgcn_mfma_f32_32x32x16_bf16(k1, qf[c], S1, 0, 0, 0);
    }
    __builtin_amdgcn_s_setprio(0);
  };

  auto pv = [&](int kt) {
    const char* Vd = vbuf(kt);
    __builtin_amdgcn_s_setprio(1);
#pragma unroll
    for (int db = 0; db < 2; ++db)
#pragma unroll
      for (int kvc = 0; kvc < 4; ++kvc) {
        short8 vf = *(const short8*)(Vd + koff[db * 4 + kvc]);
        if (db == 0)
          O0 = __builtin_amdgcn_mfma_f32_32x32x16_bf16(vf, pf[kvc], O0, 0, 0, 0);
        else
          O1 = __builtin_amdgcn_mfma_f32_32x32x16_bf16(vf, pf[kvc], O1, 0, 0, 0);
      }
    __builtin_amdgcn_s_setprio(0);
  };

  auto softmax_pack = [&](const f32x16& S0, const f32x16& S1) {
    unsigned pk0[8], pk1[8];
#pragma unroll
    for (int j = 0; j < 8; ++j) {
      int r = j * 2;
      float a0 = __builtin_amdgcn_exp2f(S0[r]);
      float a1 = __builtin_amdgcn_exp2f(S0[r + 1]);
      float b0 = __builtin_amdgcn_exp2f(S1[r]);
      float b1 = __builtin_amdgcn_exp2f(S1[r + 1]);
      lsA += a0 + a1;
      lsB += b0 + b1;
      pk0[j] = cvtpk(a0, a1);
      pk1[j] = cvtpk(b0, b1);
    }
#pragma unroll
    for (int kc = 0; kc < 2; ++kc) {
      unsigned a0 = pk0[kc * 4 + 0], a2 = pk0[kc * 4 + 2];
      unsigned a1 = pk0[kc * 4 + 1], a3 = pk0[kc * 4 + 3];
      asm("v_permlane32_swap_b32 %0, %1" : "+v"(a0), "+v"(a2));
      asm("v_permlane32_swap_b32 %0, %1" : "+v"(a1), "+v"(a3));
      unsigned b0 = pk1[kc * 4 + 0], b2 = pk1[kc * 4 + 2];
      unsigned b1 = pk1[kc * 4 + 1], b3 = pk1[kc * 4 + 3];
      asm("v_permlane32_swap_b32 %0, %1" : "+v"(b0), "+v"(b2));
      asm("v_permlane32_swap_b32 %0, %1" : "+v"(b1), "+v"(b3));
      u32x4 fa, fb;
      fa[0] = a0; fa[1] = a1; fa[2] = a2; fa[3] = a3;
      fb[0] = b0; fb[1] = b1; fb[2] = b2; fb[3] = b3;
      pf[kc] = __builtin_bit_cast(short8, fa);
      pf[2 + kc] = __builtin_bit_cast(short8, fb);
    }
  };

  // ---- pipeline: stage 2 ahead; PV deferred one tile behind QK (v11 schedule) ----
  stage(0);
  stage(1);
  asm volatile("s_waitcnt vmcnt(2)" ::: "memory");  // stage(0) retired
  __builtin_amdgcn_s_barrier();
  stage(2);
  {
    f32x16 S0{}, S1{};
    qk(0, S0, S1);
    softmax_pack(S0, S1);
  }
  for (int kt = 1; kt < 31; ++kt) {
    asm volatile("s_waitcnt vmcnt(2)" ::: "memory");  // stage(kt) retired
    __builtin_amdgcn_s_barrier();                     // all waves' reads of V(kt-2)/K(kt-1) done
    if (kt < 30) stage(kt + 2);
    f32x16 S0{}, S1{};
    qk(kt, S0, S1);               // issue; results consumed below
    pv(kt - 1);                   // independent: pf(kt-1) + V(kt-1) ready
    softmax_pack(S0, S1);         // VALU overlaps MFMA drain
  }
  asm volatile("s_waitcnt vmcnt(0)" ::: "memory");
  __builtin_amdgcn_s_barrier();
  {
    f32x16 S0{}, S1{};
    qk(31, S0, S1);
    pv(30);
    softmax_pack(S0, S1);
  }
  pv(31);
  __builtin_amdgcn_s_barrier();  // all reads done before epilogue scratch reuse

  // epilogue: combine partner-lane lsum, normalize, bounce O^T -> O via LDS
  float lsum = lsA + lsB;
  lsum += __shfl_xor(lsum, 32);
  float linv = 1.0f / lsum;
  unsigned short* Ow = smem + w * 2048;  // 4KB per wave (32 rows x 128B), 8 waves = 32KB
#pragma unroll
  for (int db = 0; db < 2; ++db)
#pragma unroll
    for (int rp = 0; rp < 8; ++rp) {
      int r = rp * 2;
      float a = (db == 0 ? O0[r] : O1[r]) * linv;
      float b2 = (db == 0 ? O0[r + 1] : O1[r + 1]) * linv;
      unsigned wv = cvtpk(a, b2);
      int dd = db * 32 + (r & 3) + 8 * (r >> 2) + 4 * hi;  // even d
      int byteo = (q31 * 128 + (dd >> 1) * 4) ^ ((q31 & 7) << 4);
      *(unsigned*)((char*)Ow + byteo) = wv;
    }
#pragma unroll
  for (int i = 0; i < 4; ++i) {
    int qq = i * 8 + (l >> 3), slot = l & 7;
    int byteo = (qq * 128 + slot * 16) ^ ((qq & 7) << 4);
    short8 ov = *(const short8*)((const char*)Ow + byteo);
    *(short8*)(Ctx + (size_t)(b * Tt + qbase + qq) * Fd + h * Dk + slot * 8) = ov;
  }
}

// ---------------- LayerNorm (in place on d_out; residual already added) ----------------
__global__ __launch_bounds__(256) void ln_res(
    float* __restrict__ xo, const float* __restrict__ gamma, const float* __restrict__ beta) {
  int row = blockIdx.x, t = threadIdx.x;
  float4 xv = ((const float4*)(xo + (size_t)row * Fd))[t];
  float x0 = xv.x, x1 = xv.y, x2 = xv.z, x3 = xv.w;
  float s = x0 + x1 + x2 + x3;
  float ss = x0 * x0 + x1 * x1 + x2 * x2 + x3 * x3;
#pragma unroll
  for (int off = 32; off >= 1; off >>= 1) {
    s += __shfl_xor(s, off);
    ss += __shfl_xor(ss, off);
  }
  __shared__ float rs_[4], rss[4];
  int w = t >> 6, l = t & 63;
  if (l == 0) { rs_[w] = s; rss[w] = ss; }
  __syncthreads();
  s = rs_[0] + rs_[1] + rs_[2] + rs_[3];
  ss = rss[0] + rss[1] + rss[2] + rss[3];
  float mu = s * (1.0f / 1024.0f);
  float var = ss * (1.0f / 1024.0f) - mu * mu;
  float rstd = rsqrtf(var + 1e-5f);
  float4 gv = ((const float4*)gamma)[t];
  float4 bv = ((const float4*)beta)[t];
  float4 o;
  o.x = (x0 - mu) * rstd * gv.x + bv.x;
  o.y = (x1 - mu) * rstd * gv.y + bv.y;
  o.z = (x2 - mu) * rstd * gv.z + bv.z;
  o.w = (x3 - mu) * rstd * gv.w + bv.w;
  ((float4*)(xo + (size_t)row * Fd))[t] = o;
}

extern "C" void kernel_launch(void* const* d_in, const int* in_sizes, int n_in,
                              void* d_out, int out_size, void* d_ws, size_t ws_size,
                              hipStream_t stream) {
  (void)in_sizes; (void)n_in; (void)out_size; (void)ws_size;
  const float* key   = (const float*)d_in[0];
  const float* value = (const float*)d_in[1];
  const float* query = (const float*)d_in[2];
  const float* Wq = (const float*)d_in[3];
  const float* bq = (const float*)d_in[4];
  const float* Wk = (const float*)d_in[5];
  const float* bk = (const float*)d_in[6];
  const float* Wv = (const float*)d_in[7];
  const float* bv_ = (const float*)d_in[8];
  const float* Wo = (const float*)d_in[9];
  const float* bo = (const float*)d_in[10];
  const float* ln_g = (const float*)d_in[11];
  const float* ln_b = (const float*)d_in[12];
  float* out = (float*)d_out;

  char* ws = (char*)d_ws;
  size_t off = 0;
  auto alloc = [&](size_t bytes) {
    char* p = ws + off;
    off += (bytes + 255) & ~(size_t)255;
    return p;
  };
  const size_t MF = (size_t)Mrows * Fd;  // 8M elems
  unsigned short* Qb  = (unsigned short*)alloc(MF * 2);
  unsigned short* Kbf = (unsigned short*)alloc(MF * 2);
  unsigned short* Vtb = (unsigned short*)alloc(MF * 2);  // V^T, written by gemm_qkvf z==2
  unsigned short* Ctx = (unsigned short*)alloc(MF * 2);
  unsigned short* wqb = (unsigned short*)alloc((size_t)Fd * Fd * 2);
  unsigned short* wkb = (unsigned short*)alloc((size_t)Fd * Fd * 2);
  unsigned short* wvb = (unsigned short*)alloc((size_t)Fd * Fd * 2);
  unsigned short* wob = (unsigned short*)alloc((size_t)Fd * Fd * 2);

  cvt4_bf16<<<dim3(256, 4), 256, 0, stream>>>(Wq, wqb, Wk, wkb, Wv, wvb, Wo, wob, (Fd * Fd) / 4);

  gemm_qkvf<<<dim3(Fd / 256, Mrows / 128, 3), 512, 0, stream>>>(
      query, key, value, wqb, wkb, wvb, bq, bk, bv_, Qb, Kbf, Vtb);

  attn_kernel<<<Bz * Hh * (Tt / 256), 512, 0, stream>>>(Qb, Kbf, Vtb, Ctx);

  gemm_out<<<dim3(Fd / 128, Mrows / 128), 256, 0, stream>>>(Ctx, wob, bo, query, out);
  ln_res<<<Mrows, 256, 0, stream>>>(out, ln_g, ln_b);
}

// Round 11
// 177.474 us; speedup vs baseline: 1.0194x; 1.0194x over previous
//
#include <hip/hip_runtime.h>
#include <hip/hip_bf16.h>
#include <cstdint>
#include <cstddef>

#define DEVI __device__ __forceinline__

typedef __attribute__((ext_vector_type(8))) short short8;
typedef __attribute__((ext_vector_type(4))) float f32x4;
typedef __attribute__((ext_vector_type(16))) float f32x16;
typedef __attribute__((ext_vector_type(4))) unsigned int u32x4;

constexpr int Bz = 4, Tt = 2048, Fd = 1024, Hh = 16, Dk = 64;
constexpr int Mrows = Bz * Tt;  // 8192
constexpr float QSCALE = 0.18033688011112042f;  // (1/8) * log2(e)

DEVI unsigned short f2bf(float f) {
  union { __hip_bfloat16 h; unsigned short u; } cv;
  cv.h = __float2bfloat16(f);
  return cv.u;
}

DEVI unsigned cvtpk(float a, float b) {  // low = a, high = b, RNE
  unsigned r;
  asm("v_cvt_pk_bf16_f32 %0, %1, %2" : "=v"(r) : "v"(a), "v"(b));
  return r;
}

DEVI void gl_lds16(const void* g, void* s) {
  __builtin_amdgcn_global_load_lds(
      (const __attribute__((address_space(1))) void*)g,
      (__attribute__((address_space(3))) void*)s, 16, 0, 0);
}

// 4 weight matrices fp32->bf16, one launch
__global__ void cvt4_bf16(const float* __restrict__ s0, unsigned short* __restrict__ d0,
                          const float* __restrict__ s1, unsigned short* __restrict__ d1,
                          const float* __restrict__ s2, unsigned short* __restrict__ d2,
                          const float* __restrict__ s3, unsigned short* __restrict__ d3,
                          int n4) {
  const float* src = blockIdx.y == 0 ? s0 : (blockIdx.y == 1 ? s1 : (blockIdx.y == 2 ? s2 : s3));
  unsigned short* dst = blockIdx.y == 0 ? d0 : (blockIdx.y == 1 ? d1 : (blockIdx.y == 2 ? d2 : d3));
  int i = blockIdx.x * blockDim.x + threadIdx.x;
  int stride = gridDim.x * blockDim.x;
  for (; i < n4; i += stride) {
    float4 v = reinterpret_cast<const float4*>(src)[i];
    ushort4 o;
    o.x = f2bf(v.x); o.y = f2bf(v.y); o.z = f2bf(v.z); o.w = f2bf(v.w);
    reinterpret_cast<ushort4*>(dst)[i] = o;
  }
}

// -------- QKV GEMM, fused fp32->bf16 A conversion, 128x256 tile @ 512 threads --------
// [R9 proven best] 8 waves (2Mx4N), acc[4][4] (60 VGPR), 48KB LDS, 3 blocks/CU;
// conversion redundancy 4 (vs 8 at BN=128). R1 dbuf / R5 hoist / R6 BN=256@256t /
// R10 alternatives all bracketed worse. grid.z: 0=Q (scaled), 1=K, 2=V (transposed).
__global__ __launch_bounds__(512, 2) void gemm_qkvf(
    const float* __restrict__ q32, const float* __restrict__ k32,
    const float* __restrict__ v32, const unsigned short* __restrict__ wq,
    const unsigned short* __restrict__ wk, const unsigned short* __restrict__ wv,
    const float* __restrict__ bq, const float* __restrict__ bk, const float* __restrict__ bv,
    unsigned short* __restrict__ Qb, unsigned short* __restrict__ Kb,
    unsigned short* __restrict__ Vt) {
  constexpr int K = 1024, N = 1024;
  __shared__ __align__(16) unsigned short As[128 * 64];   // 16KB
  __shared__ __align__(16) unsigned short Bs[256 * 64];   // 32KB
  int z = blockIdx.z;
  const float* A32 = z == 0 ? q32 : (z == 1 ? k32 : v32);
  const unsigned short* W = z == 0 ? wq : (z == 1 ? wk : wv);
  const float* bias = z == 0 ? bq : (z == 1 ? bk : bv);
  void* out = z == 0 ? (void*)Qb : (z == 1 ? (void*)Kb : (void*)Vt);
  float scale = z == 0 ? QSCALE : 1.0f;
  int mode = z == 2 ? 2 : 0;

  int f = blockIdx.y * gridDim.x + blockIdx.x;  // 0..255 (64 m-blocks x 4 n-blocks)
  f = (f & 7) * 32 + (f >> 3);                  // XCD-contiguous chunks (256 = 8x32, bijective)
  const int m0 = (f >> 2) * 128, n0 = (f & 3) * 256;
  const int t = threadIdx.x, w = t >> 6, l = t & 63;
  const int wr = w >> 2, wc = w & 3;            // 2 M-waves x 4 N-waves, 64x64 each
  const int lr = l & 15, lg = l >> 4;
  f32x4 acc[4][4] = {};

  for (int k0 = 0; k0 < K; k0 += 64) {
    __syncthreads();
    // A fp32 loads first (latency overlaps B issue): 128 rows, 512 threads
    float4 fA[2][2];
#pragma unroll
    for (int i = 0; i < 2; ++i) {
      int row = i * 64 + w * 8 + (l >> 3);
      const float* src = A32 + (size_t)(m0 + row) * K + k0 + (l & 7) * 8;
      fA[i][0] = ((const float4*)src)[0];
      fA[i][1] = ((const float4*)src)[1];
    }
    // B via global_load_lds (pre-swizzled source, linear dest): 256 rows x 64 cols
#pragma unroll
    for (int i = 0; i < 4; ++i) {
      int base = i * 8192 + w * 1024;
      int d = base + l * 16;
      int row = d >> 7;
      int srcb = ((l & 7) ^ (row & 7)) << 4;
      gl_lds16((const char*)W + ((size_t)(n0 + row) * K + k0) * 2 + srcb, (char*)Bs + base);
    }
    // A: cvt_pk + swizzled ds_write_b128
#pragma unroll
    for (int i = 0; i < 2; ++i) {
      int row = i * 64 + w * 8 + (l >> 3);
      u32x4 wv4;
      wv4[0] = cvtpk(fA[i][0].x, fA[i][0].y);
      wv4[1] = cvtpk(fA[i][0].z, fA[i][0].w);
      wv4[2] = cvtpk(fA[i][1].x, fA[i][1].y);
      wv4[3] = cvtpk(fA[i][1].z, fA[i][1].w);
      int slot = (l & 7) ^ (row & 7);
      *(u32x4*)((char*)As + row * 128 + slot * 16) = wv4;
    }
    __syncthreads();
#pragma unroll
    for (int kk = 0; kk < 2; ++kk) {
      short8 af[4], bf[4];
#pragma unroll
      for (int i = 0; i < 4; ++i) {
        int ra = wr * 64 + i * 16 + lr;
        int rb = wc * 64 + i * 16 + lr;
        af[i] = *(const short8*)((const char*)As + ra * 128 + (((kk * 4 + lg) ^ (ra & 7)) << 4));
        bf[i] = *(const short8*)((const char*)Bs + rb * 128 + (((kk * 4 + lg) ^ (rb & 7)) << 4));
      }
#pragma unroll
      for (int mi = 0; mi < 4; ++mi)
#pragma unroll
        for (int ni = 0; ni < 4; ++ni)
          acc[mi][ni] = __builtin_amdgcn_mfma_f32_16x16x32_bf16(af[mi], bf[ni], acc[mi][ni], 0, 0, 0);
    }
  }
#pragma unroll
  for (int mi = 0; mi < 4; ++mi)
#pragma unroll
    for (int ni = 0; ni < 4; ++ni) {
      int col = n0 + wc * 64 + ni * 16 + lr;
      float bv = bias[col];
      if (mode == 2) {
        // transposed store into Vt[((b*16+h)*64+d)*2048 + t], 4 consecutive t
        int hh = col >> 6, dd = col & 63;
        int row = m0 + wr * 64 + mi * 16 + lg * 4;
        int bb = row >> 11, t0 = row & 2047;
        ushort4 o;
        o.x = f2bf(acc[mi][ni][0] + bv);
        o.y = f2bf(acc[mi][ni][1] + bv);
        o.z = f2bf(acc[mi][ni][2] + bv);
        o.w = f2bf(acc[mi][ni][3] + bv);
        *(ushort4*)((unsigned short*)out + (((size_t)(bb * Hh + hh) * Dk + dd) << 11) + t0) = o;
      } else {
#pragma unroll
        for (int r = 0; r < 4; ++r) {
          int row = m0 + wr * 64 + mi * 16 + lg * 4 + r;
          ((unsigned short*)out)[(size_t)row * N + col] = f2bf((acc[mi][ni][r] + bv) * scale);
        }
      }
    }
}

// output projection + residual: out = A @ Wo^T + bo + resid (f32)  [proven]
__global__ __launch_bounds__(256, 2) void gemm_out(
    const unsigned short* __restrict__ A, const unsigned short* __restrict__ W,
    const float* __restrict__ bias, const float* __restrict__ resid,
    float* __restrict__ out) {
  constexpr int K = 1024, N = 1024;
  __shared__ __align__(16) unsigned short As[128 * 64];
  __shared__ __align__(16) unsigned short Bs[128 * 64];
  int f = blockIdx.y * gridDim.x + blockIdx.x;
  f = (f & 7) * 64 + (f >> 3);
  const int m0 = (f >> 3) * 128, n0 = (f & 7) * 128;
  const int t = threadIdx.x, w = t >> 6, l = t & 63;
  const int wr = w >> 1, wc = w & 1;
  const int lr = l & 15, lg = l >> 4;
  f32x4 acc[4][4] = {};
  for (int k0 = 0; k0 < K; k0 += 64) {
    __syncthreads();
#pragma unroll
    for (int i = 0; i < 4; ++i) {
      int base = i * 4096 + w * 1024;
      int d = base + l * 16;
      int row = d >> 7;
      int srcb = ((l & 7) ^ (row & 7)) << 4;
      gl_lds16((const char*)A + ((size_t)(m0 + row) * K + k0) * 2 + srcb, (char*)As + base);
      gl_lds16((const char*)W + ((size_t)(n0 + row) * K + k0) * 2 + srcb, (char*)Bs + base);
    }
    __syncthreads();
#pragma unroll
    for (int kk = 0; kk < 2; ++kk) {
      short8 af[4], bf[4];
#pragma unroll
      for (int i = 0; i < 4; ++i) {
        int ra = wr * 64 + i * 16 + lr;
        int rb = wc * 64 + i * 16 + lr;
        af[i] = *(const short8*)((const char*)As + ra * 128 + (((kk * 4 + lg) ^ (ra & 7)) << 4));
        bf[i] = *(const short8*)((const char*)Bs + rb * 128 + (((kk * 4 + lg) ^ (rb & 7)) << 4));
      }
#pragma unroll
      for (int mi = 0; mi < 4; ++mi)
#pragma unroll
        for (int ni = 0; ni < 4; ++ni)
          acc[mi][ni] = __builtin_amdgcn_mfma_f32_16x16x32_bf16(af[mi], bf[ni], acc[mi][ni], 0, 0, 0);
    }
  }
#pragma unroll
  for (int mi = 0; mi < 4; ++mi)
#pragma unroll
    for (int ni = 0; ni < 4; ++ni) {
      int col = n0 + wc * 64 + ni * 16 + lr;
      float bv = bias[col];
#pragma unroll
      for (int r = 0; r < 4; ++r) {
        int row = m0 + wr * 64 + mi * 16 + lg * 4 + r;
        size_t idx = (size_t)row * N + col;
        out[idx] = acc[mi][ni][r] + bv + resid[idx];
      }
    }
}

// ---------------- Flash attention v13: pair-per-barrier ring-8 [R9 proven] ----------------
// 8 waves x 64 q-rows, 512 q-rows/block, XCD-affinity mapping. Ring-8 K/V LDS
// (128KB), stage 4 tiles ahead, two tiles per barrier, deferred PV. At its
// VALU+MFMA floor (R3/R7/R10 schedule variants all <= this).
__global__ __launch_bounds__(512, 2) void attn_kernel(
    const unsigned short* __restrict__ Qb, const unsigned short* __restrict__ Kb,
    const unsigned short* __restrict__ Vt, unsigned short* __restrict__ Ctx) {
  __shared__ __align__(16) unsigned short smem[16 * 4096];  // 128KB: K slots [0..8), V slots at +64KB
  int bid = blockIdx.x;
  const int xcd = bid & 7, idx = bid >> 3;   // hw round-robins blocks across 8 XCDs
  const int bh = xcd * 8 + (idx >> 2);       // 8 heads per XCD
  const int q0 = (idx & 3) * 512;            // 4 q-blocks per head, same XCD
  const int h = bh & 15;
  const int b = bh >> 4;
  const int t = threadIdx.x, w = t >> 6, l = t & 63;
  const int q31 = l & 31, hi = l >> 5;
  const int qbase = q0 + w * 64;

  short8 qfA[4], qfB[4];
  {
    const unsigned short* qpA = Qb + (size_t)(b * Tt + qbase + q31) * Fd + h * Dk;
    const unsigned short* qpB = qpA + (size_t)32 * Fd;
#pragma unroll
    for (int c = 0; c < 4; ++c) {
      qfA[c] = *(const short8*)(qpA + c * 16 + hi * 8);
      qfB[c] = *(const short8*)(qpB + c * 16 + hi * 8);
    }
  }

  int koff[8];
#pragma unroll
  for (int g = 0; g < 2; ++g)
#pragma unroll
    for (int c = 0; c < 4; ++c) {
      int row = g * 32 + q31;
      koff[g * 4 + c] = row * 128 + ((c * 32 + hi * 16) ^ ((row & 7) << 4));
    }

  const size_t kbase = (size_t)(b * Tt) * Fd + h * Dk;
  const size_t vbase = (size_t)((b * Hh + h) * Dk) * Tt;

  f32x16 OA0{}, OA1{}, OB0{}, OB1{};
  short8 pfA[4], pfB[4];  // packed P(t-1), carried between pv calls
  float lsA0 = 0.f, lsB0 = 0.f, lsA1 = 0.f, lsB1 = 0.f;

  auto kbuf = [&](int kt) { return (const char*)smem + ((kt & 7) << 13); };
  auto vbuf = [&](int kt) { return (const char*)smem + 65536 + ((kt & 7) << 13); };

  auto stage = [&](int kt) {
    char* Kd = (char*)smem + ((kt & 7) << 13);
    char* Vd = (char*)smem + 65536 + ((kt & 7) << 13);
    int base = w * 1024;
    int d0 = base + l * 16;
    int row = d0 >> 7, inb = d0 & 127;
    int srcb = inb ^ ((row & 7) << 4);
    gl_lds16((const char*)Kb + (kbase + (size_t)(kt * 64 + row) * Fd) * 2 + srcb, Kd + base);
    gl_lds16((const char*)Vt + (vbase + (size_t)row * Tt + kt * 64) * 2 + srcb, Vd + base);
  };

  auto qk = [&](int kt, f32x16& S0a, f32x16& S1a, f32x16& S0b, f32x16& S1b) {
    const char* Kd = kbuf(kt);
    __builtin_amdgcn_s_setprio(1);
#pragma unroll
    for (int c = 0; c < 4; ++c) {
      short8 k0 = *(const short8*)(Kd + koff[c]);
      short8 k1 = *(const short8*)(Kd + koff[4 + c]);
      S0a = __builtin_amdgcn_mfma_f32_32x32x16_bf16(k0, qfA[c], S0a, 0, 0, 0);
      S1a = __builtin_amdgcn_mfma_f32_32x32x16_bf16(k1, qfA[c], S1a, 0, 0, 0);
      S0b = __builtin_amdgcn_mfma_f32_32x32x16_bf16(k0, qfB[c], S0b, 0, 0, 0);
      S1b = __builtin_amdgcn_mfma_f32_32x32x16_bf16(k1, qfB[c], S1b, 0, 0, 0);
    }
    __builtin_amdgcn_s_setprio(0);
  };

  auto pv = [&](int kt) {
    const char* Vd = vbuf(kt);
    __builtin_amdgcn_s_setprio(1);
#pragma unroll
    for (int db = 0; db < 2; ++db)
#pragma unroll
      for (int kvc = 0; kvc < 4; ++kvc) {
        short8 vf = *(const short8*)(Vd + koff[db * 4 + kvc]);
        if (db == 0) {
          OA0 = __builtin_amdgcn_mfma_f32_32x32x16_bf16(vf, pfA[kvc], OA0, 0, 0, 0);
          OB0 = __builtin_amdgcn_mfma_f32_32x32x16_bf16(vf, pfB[kvc], OB0, 0, 0, 0);
        } else {
          OA1 = __builtin_amdgcn_mfma_f32_32x32x16_bf16(vf, pfA[kvc], OA1, 0, 0, 0);
          OB1 = __builtin_amdgcn_mfma_f32_32x32x16_bf16(vf, pfB[kvc], OB1, 0, 0, 0);
        }
      }
    __builtin_amdgcn_s_setprio(0);
  };

  auto softmax_pack = [&](const f32x16& S0, const f32x16& S1, float& lsA, float& lsB, short8* pf) {
    unsigned pk0[8], pk1[8];
#pragma unroll
    for (int j = 0; j < 8; ++j) {
      int r = j * 2;
      float a0 = __builtin_amdgcn_exp2f(S0[r]);
      float a1 = __builtin_amdgcn_exp2f(S0[r + 1]);
      float b0 = __builtin_amdgcn_exp2f(S1[r]);
      float b1 = __builtin_amdgcn_exp2f(S1[r + 1]);
      lsA += a0 + a1;
      lsB += b0 + b1;
      pk0[j] = cvtpk(a0, a1);
      pk1[j] = cvtpk(b0, b1);
    }
#pragma unroll
    for (int kc = 0; kc < 2; ++kc) {
      unsigned a0 = pk0[kc * 4 + 0], a2 = pk0[kc * 4 + 2];
      unsigned a1 = pk0[kc * 4 + 1], a3 = pk0[kc * 4 + 3];
      asm("v_permlane32_swap_b32 %0, %1" : "+v"(a0), "+v"(a2));
      asm("v_permlane32_swap_b32 %0, %1" : "+v"(a1), "+v"(a3));
      unsigned b0 = pk1[kc * 4 + 0], b2 = pk1[kc * 4 + 2];
      unsigned b1 = pk1[kc * 4 + 1], b3 = pk1[kc * 4 + 3];
      asm("v_permlane32_swap_b32 %0, %1" : "+v"(b0), "+v"(b2));
      asm("v_permlane32_swap_b32 %0, %1" : "+v"(b1), "+v"(b3));
      u32x4 fa, fb;
      fa[0] = a0; fa[1] = a1; fa[2] = a2; fa[3] = a3;
      fb[0] = b0; fb[1] = b1; fb[2] = b2; fb[3] = b3;
      pf[kc] = __builtin_bit_cast(short8, fa);
      pf[2 + kc] = __builtin_bit_cast(short8, fb);
    }
  };

  // ---- pair-per-barrier pipeline: stage 4 tiles ahead, 2 tiles per barrier ----
  stage(0); stage(1); stage(2); stage(3);
  asm volatile("s_waitcnt vmcnt(4)" ::: "memory");  // tiles 0,1 retired
  __builtin_amdgcn_s_barrier();
  stage(4); stage(5);
  {
    f32x16 S0a{}, S1a{}, S0b{}, S1b{};
    qk(0, S0a, S1a, S0b, S1b);
    softmax_pack(S0a, S1a, lsA0, lsB0, pfA);
    softmax_pack(S0b, S1b, lsA1, lsB1, pfB);
  }
  {
    f32x16 S0a{}, S1a{}, S0b{}, S1b{};
    qk(1, S0a, S1a, S0b, S1b);
    pv(0);
    softmax_pack(S0a, S1a, lsA0, lsB0, pfA);
    softmax_pack(S0b, S1b, lsA1, lsB1, pfB);
  }
  for (int p = 1; p < 15; ++p) {
    asm volatile("s_waitcnt vmcnt(4)" ::: "memory");  // tiles 2p,2p+1 retired
    __builtin_amdgcn_s_barrier();
    if (p < 14) { stage(2 * p + 4); stage(2 * p + 5); }
    {
      f32x16 S0a{}, S1a{}, S0b{}, S1b{};
      qk(2 * p, S0a, S1a, S0b, S1b);
      pv(2 * p - 1);
      softmax_pack(S0a, S1a, lsA0, lsB0, pfA);
      softmax_pack(S0b, S1b, lsA1, lsB1, pfB);
    }
    {
      f32x16 S0a{}, S1a{}, S0b{}, S1b{};
      qk(2 * p + 1, S0a, S1a, S0b, S1b);
      pv(2 * p);
      softmax_pack(S0a, S1a, lsA0, lsB0, pfA);
      softmax_pack(S0b, S1b, lsA1, lsB1, pfB);
    }
  }
  asm volatile("s_waitcnt vmcnt(0)" ::: "memory");  // tiles 30,31 retired
  __builtin_amdgcn_s_barrier();
  {
    f32x16 S0a{}, S1a{}, S0b{}, S1b{};
    qk(30, S0a, S1a, S0b, S1b);
    pv(29);
    softmax_pack(S0a, S1a, lsA0, lsB0, pfA);
    softmax_pack(S0b, S1b, lsA1, lsB1, pfB);
  }
  {
    f32x16 S0a{}, S1a{}, S0b{}, S1b{};
    qk(31, S0a, S1a, S0b, S1b);
    pv(30);
    softmax_pack(S0a, S1a, lsA0, lsB0, pfA);
    softmax_pack(S0b, S1b, lsA1, lsB1, pfB);
  }
  pv(31);
  __builtin_amdgcn_s_barrier();  // all reads done before epilogue scratch reuse

  // epilogue: combine partner-lane lsum per q-group, normalize, bounce O^T -> O via LDS
  float ls0 = lsA0 + lsB0;
  ls0 += __shfl_xor(ls0, 32);
  float linv0 = 1.0f / ls0;
  float ls1 = lsA1 + lsB1;
  ls1 += __shfl_xor(ls1, 32);
  float linv1 = 1.0f / ls1;
  unsigned short* Ow = smem + w * 4096;  // 8KB per wave (64 rows x 128B), 8 waves = 64KB
#pragma unroll
  for (int g = 0; g < 2; ++g) {
    float linv = g == 0 ? linv0 : linv1;
    int rowq = g * 32 + q31;
#pragma unroll
    for (int db = 0; db < 2; ++db)
#pragma unroll
      for (int rp = 0; rp < 8; ++rp) {
        int r = rp * 2;
        float a, b2;
        if (g == 0) {
          a = (db == 0 ? OA0[r] : OA1[r]) * linv;
          b2 = (db == 0 ? OA0[r + 1] : OA1[r + 1]) * linv;
        } else {
          a = (db == 0 ? OB0[r] : OB1[r]) * linv;
          b2 = (db == 0 ? OB0[r + 1] : OB1[r + 1]) * linv;
        }
        unsigned wv = cvtpk(a, b2);
        int dd = db * 32 + (r & 3) + 8 * (r >> 2) + 4 * hi;  // even d
        int byteo = (rowq * 128 + (dd >> 1) * 4) ^ ((rowq & 7) << 4);
        *(unsigned*)((char*)Ow + byteo) = wv;
      }
  }
#pragma unroll
  for (int i = 0; i < 8; ++i) {
    int qq = i * 8 + (l >> 3), slot = l & 7;
    int byteo = (qq * 128 + slot * 16) ^ ((qq & 7) << 4);
    short8 ov = *(const short8*)((const char*)Ow + byteo);
    *(short8*)(Ctx + (size_t)(b * Tt + qbase + qq) * Fd + h * Dk + slot * 8) = ov;
  }
}

// ---------------- LayerNorm (in place on d_out; residual already added) ----------------
__global__ __launch_bounds__(256) void ln_res(
    float* __restrict__ xo, const float* __restrict__ gamma, const float* __restrict__ beta) {
  int row = blockIdx.x, t = threadIdx.x;
  float4 xv = ((const float4*)(xo + (size_t)row * Fd))[t];
  float x0 = xv.x, x1 = xv.y, x2 = xv.z, x3 = xv.w;
  float s = x0 + x1 + x2 + x3;
  float ss = x0 * x0 + x1 * x1 + x2 * x2 + x3 * x3;
#pragma unroll
  for (int off = 32; off >= 1; off >>= 1) {
    s += __shfl_xor(s, off);
    ss += __shfl_xor(ss, off);
  }
  __shared__ float rs_[4], rss[4];
  int w = t >> 6, l = t & 63;
  if (l == 0) { rs_[w] = s; rss[w] = ss; }
  __syncthreads();
  s = rs_[0] + rs_[1] + rs_[2] + rs_[3];
  ss = rss[0] + rss[1] + rss[2] + rss[3];
  float mu = s * (1.0f / 1024.0f);
  float var = ss * (1.0f / 1024.0f) - mu * mu;
  float rstd = rsqrtf(var + 1e-5f);
  float4 gv = ((const float4*)gamma)[t];
  float4 bv = ((const float4*)beta)[t];
  float4 o;
  o.x = (x0 - mu) * rstd * gv.x + bv.x;
  o.y = (x1 - mu) * rstd * gv.y + bv.y;
  o.z = (x2 - mu) * rstd * gv.z + bv.z;
  o.w = (x3 - mu) * rstd * gv.w + bv.w;
  ((float4*)(xo + (size_t)row * Fd))[t] = o;
}

extern "C" void kernel_launch(void* const* d_in, const int* in_sizes, int n_in,
                              void* d_out, int out_size, void* d_ws, size_t ws_size,
                              hipStream_t stream) {
  (void)in_sizes; (void)n_in; (void)out_size; (void)ws_size;
  const float* key   = (const float*)d_in[0];
  const float* value = (const float*)d_in[1];
  const float* query = (const float*)d_in[2];
  const float* Wq = (const float*)d_in[3];
  const float* bq = (const float*)d_in[4];
  const float* Wk = (const float*)d_in[5];
  const float* bk = (const float*)d_in[6];
  const float* Wv = (const float*)d_in[7];
  const float* bv_ = (const float*)d_in[8];
  const float* Wo = (const float*)d_in[9];
  const float* bo = (const float*)d_in[10];
  const float* ln_g = (const float*)d_in[11];
  const float* ln_b = (const float*)d_in[12];
  float* out = (float*)d_out;

  char* ws = (char*)d_ws;
  size_t off = 0;
  auto alloc = [&](size_t bytes) {
    char* p = ws + off;
    off += (bytes + 255) & ~(size_t)255;
    return p;
  };
  const size_t MF = (size_t)Mrows * Fd;  // 8M elems
  unsigned short* Qb  = (unsigned short*)alloc(MF * 2);
  unsigned short* Kbf = (unsigned short*)alloc(MF * 2);
  unsigned short* Vtb = (unsigned short*)alloc(MF * 2);  // V^T, written by gemm_qkvf z==2
  unsigned short* Ctx = (unsigned short*)alloc(MF * 2);
  unsigned short* wqb = (unsigned short*)alloc((size_t)Fd * Fd * 2);
  unsigned short* wkb = (unsigned short*)alloc((size_t)Fd * Fd * 2);
  unsigned short* wvb = (unsigned short*)alloc((size_t)Fd * Fd * 2);
  unsigned short* wob = (unsigned short*)alloc((size_t)Fd * Fd * 2);

  cvt4_bf16<<<dim3(256, 4), 256, 0, stream>>>(Wq, wqb, Wk, wkb, Wv, wvb, Wo, wob, (Fd * Fd) / 4);

  gemm_qkvf<<<dim3(Fd / 256, Mrows / 128, 3), 512, 0, stream>>>(
      query, key, value, wqb, wkb, wvb, bq, bk, bv_, Qb, Kbf, Vtb);

  attn_kernel<<<Bz * Hh * (Tt / 512), 512, 0, stream>>>(Qb, Kbf, Vtb, Ctx);

  gemm_out<<<dim3(Fd / 128, Mrows / 128), 256, 0, stream>>>(Ctx, wob, bo, query, out);
  ln_res<<<Mrows, 256, 0, stream>>>(out, ln_g, ln_b);
}